// Round 1
// baseline (822.867 us; speedup 1.0000x reference)
//
#include <hip/hip_runtime.h>

typedef _Float16 f16;
typedef f16  f16x8 __attribute__((ext_vector_type(8)));
typedef float f32x4 __attribute__((ext_vector_type(4)));

#define S3     3145728LL   // elems per component buffer (12*256*16*64)
#define GELEMS 25165824LL  // 8 * S3 : elems per batch area

__device__ __forceinline__ f32x4 mm(f16x8 a, f16x8 b, f32x4 c) {
  return __builtin_amdgcn_mfma_f32_16x16x32_f16(a, b, c, 0, 0, 0);
}

// ---------------- transpose + fp32->fp16 convert: out[Cc][R] = in[R][Cc] ----
__global__ void cvt_T_kernel(const float* __restrict__ in, f16* __restrict__ out,
                             int R, int Cc) {
  __shared__ float tile[32][33];
  int tc = blockIdx.x, tr = blockIdx.y;
  int lr = threadIdx.x & 31, lw = threadIdx.x >> 5;
  int c0 = tc * 32, r0 = tr * 32;
#pragma unroll
  for (int i = 0; i < 4; i++)
    tile[lw + 8 * i][lr] = in[(size_t)(r0 + lw + 8 * i) * Cc + c0 + lr];
  __syncthreads();
#pragma unroll
  for (int i = 0; i < 4; i++)
    out[(size_t)(c0 + lw + 8 * i) * R + r0 + lr] = (f16)tile[lr][lw + 8 * i];
}

// ---------------- QKV GEMM: C[G*4096,4608] = x_f32 * w16t^T, permuted store --
__global__ __launch_bounds__(256) void gemm_qkv_kernel(
    const float* __restrict__ A,   // x chunk base, lda=768
    const f16* __restrict__ Bt,    // [4608][768] fp16 (pre-transposed w_qkv)
    f16* __restrict__ area) {
  __shared__ f16 Asm[128 * 32];
  __shared__ f16 Bsm[128 * 32];
  const int nbn = 36;
  int nwg = gridDim.x;
  int id  = blockIdx.x;
  int cpx = nwg >> 3;
  int id2 = (id & 7) * cpx + (id >> 3);          // XCD swizzle (nwg % 8 == 0)
  int sr  = id2 / (8 * nbn);
  int rr_ = id2 % (8 * nbn);
  int bm  = sr * 8 + (rr_ & 7);                  // 8-row super-groups for L2
  int bn  = rr_ >> 3;

  int tid = threadIdx.x;
  int wave = tid >> 6, lane = tid & 63;
  int l16 = lane & 15, lq = lane >> 4;
  int wr = wave >> 1, wc = wave & 1;

  int srow = tid >> 1;
  int skh  = (tid & 1) << 4;
  const float* Ap = A  + (size_t)(bm * 128 + srow) * 768 + skh;
  const f16*   Bp = Bt + (size_t)(bn * 128 + srow) * 768 + skh;
  f16* AsmW = &Asm[srow * 32 + skh];
  f16* BsmW = &Bsm[srow * 32 + skh];

  f32x4 zz = {0.f, 0.f, 0.f, 0.f};
  f32x4 acc[4][4];
#pragma unroll
  for (int m = 0; m < 4; m++)
#pragma unroll
    for (int n = 0; n < 4; n++) acc[m][n] = zz;

  for (int kt = 0; kt < 24; kt++) {
    const float* ap = Ap + kt * 32;
    f32x4 a0 = *(const f32x4*)(ap);
    f32x4 a1 = *(const f32x4*)(ap + 4);
    f32x4 a2 = *(const f32x4*)(ap + 8);
    f32x4 a3 = *(const f32x4*)(ap + 12);
    f16x8 b0 = *(const f16x8*)(Bp + kt * 32);
    f16x8 b1 = *(const f16x8*)(Bp + kt * 32 + 8);
    f16x8 av0, av1;
#pragma unroll
    for (int i = 0; i < 4; i++) {
      av0[i]     = (f16)a0[i];
      av0[4 + i] = (f16)a1[i];
      av1[i]     = (f16)a2[i];
      av1[4 + i] = (f16)a3[i];
    }
    __syncthreads();
    *(f16x8*)AsmW       = av0;
    *(f16x8*)(AsmW + 8) = av1;
    *(f16x8*)BsmW       = b0;
    *(f16x8*)(BsmW + 8) = b1;
    __syncthreads();
    f16x8 af[4], bf[4];
#pragma unroll
    for (int m = 0; m < 4; m++)
      af[m] = *(const f16x8*)&Asm[(wr * 64 + m * 16 + l16) * 32 + lq * 8];
#pragma unroll
    for (int n = 0; n < 4; n++)
      bf[n] = *(const f16x8*)&Bsm[(wc * 64 + n * 16 + l16) * 32 + lq * 8];
#pragma unroll
    for (int m = 0; m < 4; m++)
#pragma unroll
      for (int n = 0; n < 4; n++)
        acc[m][n] = mm(af[m], bf[n], acc[m][n]);
  }

  // permuting epilogue: col = s*768 + h*64 + d  (s: qc,kc,qs,ks,vc,vs)
  int g = (bm * 128) >> 12;
  size_t gbase = (size_t)g * GELEMS;
  int tok0 = (bm * 128) & 4095;
#pragma unroll
  for (int nt = 0; nt < 4; nt++) {
    int col = bn * 128 + wc * 64 + nt * 16 + l16;
    int s   = col / 768;          // wave-uniform (16-col span never crosses 768k)
    int rem = col - s * 768;
    int h   = rem >> 6;
    int d   = col & 63;
#pragma unroll
    for (int m = 0; m < 4; m++) {
#pragma unroll
      for (int r = 0; r < 4; r++) {
        int token = tok0 + wr * 64 + m * 16 + lq * 4 + r;
        int n = token >> 4, c = token & 15;
        size_t off;
        if (s == 0)      off = 0 * S3 + (size_t)(((h * 256 + n) * 16 + c) * 64 + d); // qc [h][n][c][d]
        else if (s == 1) off = 1 * S3 + (size_t)(((h * 256 + n) * 16 + c) * 64 + d); // kc
        else if (s == 2) off = 3 * S3 + (size_t)(((h * 16 + c) * 256 + n) * 64 + d); // qs [h][c][n][d]
        else if (s == 3) off = 4 * S3 + (size_t)(((h * 16 + c) * 256 + n) * 64 + d); // ks
        else if (s == 4) off = 2 * S3 + (size_t)(((h * 256 + n) * 64 + d) * 16 + c); // vc [h][n][d][c]
        else             off = 5 * S3 + (size_t)(((h * 16 + c) * 64 + d) * 256 + n); // vs [h][c][d][n]
        area[gbase + off] = (f16)acc[m][nt][r];
      }
    }
  }
}

// ---------------- spatial attention: per (g,h,c), flash over N=256 ----------
__global__ __launch_bounds__(512) void attn_spat_kernel(f16* __restrict__ area) {
  int blk = blockIdx.x;
  int g = blk / 192, rem = blk % 192;
  int h = rem >> 4, c = rem & 15;
  f16* base = area + (size_t)g * GELEMS;
  const f16* qs = base + 3 * S3 + (size_t)((h * 16 + c) * 256) * 64;
  const f16* ks = base + 4 * S3 + (size_t)((h * 16 + c) * 256) * 64;
  const f16* vs = base + 5 * S3 + (size_t)((h * 16 + c) * 64) * 256; // [d][n]
  f16* xs = base + 6 * S3 + (size_t)((h * 16 + c) * 256) * 64;

  int wave = threadIdx.x >> 6, lane = threadIdx.x & 63;
  int l16 = lane & 15, lq = lane >> 4;
  __shared__ f16 plds[8][32][40];   // +8 pad: 2-way-free banks on A-frag read

  f32x4 zz = {0.f, 0.f, 0.f, 0.f};
  f16x8 aq[2][2];
#pragma unroll
  for (int m = 0; m < 2; m++)
#pragma unroll
    for (int kd = 0; kd < 2; kd++)
      aq[m][kd] = *(const f16x8*)&qs[(size_t)(wave * 32 + m * 16 + l16) * 64 + kd * 32 + lq * 8];

  f32x4 o[2][4];
  float mrow[2][4], lrow[2][4];
#pragma unroll
  for (int m = 0; m < 2; m++) {
#pragma unroll
    for (int n = 0; n < 4; n++) o[m][n] = zz;
#pragma unroll
    for (int r = 0; r < 4; r++) { mrow[m][r] = -1e30f; lrow[m][r] = 0.f; }
  }

  for (int kc = 0; kc < 8; kc++) {
    int k0 = kc * 32;
    f16x8 bk00 = *(const f16x8*)&ks[(size_t)(k0 + l16) * 64 + lq * 8];
    f16x8 bk01 = *(const f16x8*)&ks[(size_t)(k0 + l16) * 64 + 32 + lq * 8];
    f16x8 bk10 = *(const f16x8*)&ks[(size_t)(k0 + 16 + l16) * 64 + lq * 8];
    f16x8 bk11 = *(const f16x8*)&ks[(size_t)(k0 + 16 + l16) * 64 + 32 + lq * 8];
    f32x4 st[2][2];
#pragma unroll
    for (int m = 0; m < 2; m++) {
      st[m][0] = mm(aq[m][1], bk01, mm(aq[m][0], bk00, zz));
      st[m][1] = mm(aq[m][1], bk11, mm(aq[m][0], bk10, zz));
    }
#pragma unroll
    for (int m = 0; m < 2; m++) {
#pragma unroll
      for (int r = 0; r < 4; r++) {
        float s0 = st[m][0][r] * 0.125f, s1 = st[m][1][r] * 0.125f;
        float t = fmaxf(s0, s1);
        t = fmaxf(t, __shfl_xor(t, 1));
        t = fmaxf(t, __shfl_xor(t, 2));
        t = fmaxf(t, __shfl_xor(t, 4));
        t = fmaxf(t, __shfl_xor(t, 8));
        float mold = mrow[m][r];
        float mnew = fmaxf(mold, t);
        float fac  = __expf(mold - mnew);
        mrow[m][r] = mnew;
        float p0 = __expf(s0 - mnew), p1 = __expf(s1 - mnew);
        lrow[m][r] = lrow[m][r] * fac + p0 + p1;
        o[m][0][r] *= fac; o[m][1][r] *= fac; o[m][2][r] *= fac; o[m][3][r] *= fac;
        int prow = m * 16 + lq * 4 + r;
        plds[wave][prow][l16]      = (f16)p0;
        plds[wave][prow][16 + l16] = (f16)p1;
      }
    }
    f16x8 ap0 = *(const f16x8*)&plds[wave][l16][lq * 8];
    f16x8 ap1 = *(const f16x8*)&plds[wave][16 + l16][lq * 8];
#pragma unroll
    for (int n = 0; n < 4; n++) {
      f16x8 bv = *(const f16x8*)&vs[(size_t)(n * 16 + l16) * 256 + k0 + lq * 8];
      o[0][n] = mm(ap0, bv, o[0][n]);
      o[1][n] = mm(ap1, bv, o[1][n]);
    }
  }
#pragma unroll
  for (int m = 0; m < 2; m++)
#pragma unroll
    for (int r = 0; r < 4; r++) {
      float l = lrow[m][r];
      l += __shfl_xor(l, 1);
      l += __shfl_xor(l, 2);
      l += __shfl_xor(l, 4);
      l += __shfl_xor(l, 8);
      lrow[m][r] = 1.0f / l;
    }
#pragma unroll
  for (int m = 0; m < 2; m++)
#pragma unroll
    for (int n = 0; n < 4; n++)
#pragma unroll
      for (int r = 0; r < 4; r++) {
        int row = wave * 32 + m * 16 + lq * 4 + r;
        xs[(size_t)row * 64 + n * 16 + l16] = (f16)(o[m][n][r] * lrow[m][r]);
      }
}

// ---------------- channel attention + combine: per (g,n), 12 heads ----------
__global__ __launch_bounds__(256) void attn_chan_kernel(f16* __restrict__ area) {
  int blk = blockIdx.x;
  int g = blk >> 8, n = blk & 255;
  f16* base = area + (size_t)g * GELEMS;
  int wave = threadIdx.x >> 6, lane = threadIdx.x & 63;
  int l16 = lane & 15, lq = lane >> 4;
  __shared__ f16 plds[4][16][40];
  if (lane < 16) {
#pragma unroll
    for (int j = 0; j < 16; j++) plds[wave][lane][16 + j] = (f16)0.f;  // zero K-pad
  }
  const f16* xs = base + 6 * S3;
  f16* prod = base + 7 * S3;
  f32x4 zz = {0.f, 0.f, 0.f, 0.f};
  for (int hi = 0; hi < 3; hi++) {
    int h = wave + hi * 4;
    const f16* q = base + 0 * S3 + (size_t)((h * 256 + n) * 16) * 64;
    const f16* k = base + 1 * S3 + (size_t)((h * 256 + n) * 16) * 64;
    const f16* v = base + 2 * S3 + (size_t)((h * 256 + n) * 64) * 16; // [d][c]
    f16x8 a0 = *(const f16x8*)&q[l16 * 64 + lq * 8];
    f16x8 a1 = *(const f16x8*)&q[l16 * 64 + 32 + lq * 8];
    f16x8 b0 = *(const f16x8*)&k[l16 * 64 + lq * 8];
    f16x8 b1 = *(const f16x8*)&k[l16 * 64 + 32 + lq * 8];
    f32x4 s = mm(a1, b1, mm(a0, b0, zz));
    float p[4];
#pragma unroll
    for (int r = 0; r < 4; r++) {
      float t = s[r] * 0.125f;
      float mx = t;
      mx = fmaxf(mx, __shfl_xor(mx, 1));
      mx = fmaxf(mx, __shfl_xor(mx, 2));
      mx = fmaxf(mx, __shfl_xor(mx, 4));
      mx = fmaxf(mx, __shfl_xor(mx, 8));
      float e = __expf(t - mx);
      float sum = e;
      sum += __shfl_xor(sum, 1);
      sum += __shfl_xor(sum, 2);
      sum += __shfl_xor(sum, 4);
      sum += __shfl_xor(sum, 8);
      p[r] = e / sum;
    }
#pragma unroll
    for (int r = 0; r < 4; r++)
      plds[wave][lq * 4 + r][l16] = (f16)p[r];
    f16x8 ap = *(const f16x8*)&plds[wave][l16][lq * 8]; // k>=16 are zeros
#pragma unroll
    for (int nt = 0; nt < 4; nt++) {
      f16x8 bv = *(const f16x8*)&v[(nt * 16 + l16) * 16 + lq * 8]; // overread hits finite data, x0
      f32x4 o = mm(ap, bv, zz);
#pragma unroll
      for (int r = 0; r < 4; r++) {
        int cq = lq * 4 + r, d = nt * 16 + l16;
        float xsv = (float)xs[(size_t)((h * 16 + cq) * 256 + n) * 64 + d];
        prod[(size_t)n * 12288 + h * 1024 + cq * 64 + d] = (f16)(o[r] * xsv);
      }
    }
  }
}

// ---------------- proj GEMM: out[G*4096,768] = prod * wpt^T + bias ----------
__global__ __launch_bounds__(256) void gemm_proj_kernel(
    const f16* __restrict__ area, const f16* __restrict__ Bt,
    const float* __restrict__ bias, float* __restrict__ Cout) {
  __shared__ f16 Asm[128 * 32];
  __shared__ f16 Bsm[128 * 32];
  const int nbn = 6;
  int nwg = gridDim.x;
  int id  = blockIdx.x;
  int cpx = nwg >> 3;
  int id2 = (id & 7) * cpx + (id >> 3);
  int sr  = id2 / (8 * nbn);
  int rr_ = id2 % (8 * nbn);
  int bm  = sr * 8 + (rr_ & 7);
  int bn  = rr_ >> 3;

  int tid = threadIdx.x;
  int wave = tid >> 6, lane = tid & 63;
  int l16 = lane & 15, lq = lane >> 4;
  int wr = wave >> 1, wc = wave & 1;

  int srow = tid >> 1;
  int skh  = (tid & 1) << 4;
  int g = (bm * 128) >> 12;
  const f16* Ap = area + (size_t)g * GELEMS + 7 * S3 +
                  (size_t)(((bm * 128) & 4095) + srow) * 768 + skh;
  const f16* Bp = Bt + (size_t)(bn * 128 + srow) * 768 + skh;
  f16* AsmW = &Asm[srow * 32 + skh];
  f16* BsmW = &Bsm[srow * 32 + skh];

  f32x4 zz = {0.f, 0.f, 0.f, 0.f};
  f32x4 acc[4][4];
#pragma unroll
  for (int m = 0; m < 4; m++)
#pragma unroll
    for (int n = 0; n < 4; n++) acc[m][n] = zz;

  for (int kt = 0; kt < 24; kt++) {
    f16x8 a0 = *(const f16x8*)(Ap + kt * 32);
    f16x8 a1 = *(const f16x8*)(Ap + kt * 32 + 8);
    f16x8 b0 = *(const f16x8*)(Bp + kt * 32);
    f16x8 b1 = *(const f16x8*)(Bp + kt * 32 + 8);
    __syncthreads();
    *(f16x8*)AsmW       = a0;
    *(f16x8*)(AsmW + 8) = a1;
    *(f16x8*)BsmW       = b0;
    *(f16x8*)(BsmW + 8) = b1;
    __syncthreads();
    f16x8 af[4], bf[4];
#pragma unroll
    for (int m = 0; m < 4; m++)
      af[m] = *(const f16x8*)&Asm[(wr * 64 + m * 16 + l16) * 32 + lq * 8];
#pragma unroll
    for (int n = 0; n < 4; n++)
      bf[n] = *(const f16x8*)&Bsm[(wc * 64 + n * 16 + l16) * 32 + lq * 8];
#pragma unroll
    for (int m = 0; m < 4; m++)
#pragma unroll
      for (int n = 0; n < 4; n++)
        acc[m][n] = mm(af[m], bf[n], acc[m][n]);
  }

#pragma unroll
  for (int nt = 0; nt < 4; nt++) {
    int col = bn * 128 + wc * 64 + nt * 16 + l16;
    float bb = bias[col];
#pragma unroll
    for (int m = 0; m < 4; m++) {
#pragma unroll
      for (int r = 0; r < 4; r++) {
        int row = bm * 128 + wr * 64 + m * 16 + lq * 4 + r;
        Cout[(size_t)row * 768 + col] = acc[m][nt][r] + bb;
      }
    }
  }
}

// ---------------- host ------------------------------------------------------
extern "C" void kernel_launch(void* const* d_in, const int* in_sizes, int n_in,
                              void* d_out, int out_size, void* d_ws, size_t ws_size,
                              hipStream_t stream) {
  const float* x      = (const float*)d_in[0];
  const float* w_qkv  = (const float*)d_in[1];
  const float* w_proj = (const float*)d_in[2];
  const float* b_proj = (const float*)d_in[3];
  float* out = (float*)d_out;
  f16* ws = (f16*)d_ws;

  const size_t W16T = 4608ull * 768;
  const size_t WPT  = 768ull * 768;
  f16* w16t = ws;
  f16* wpt  = ws + W16T;
  f16* area = wpt + WPT;
  size_t staticB = (W16T + WPT) * 2;

  int G = 8;  // batches per chunk; shrink until scratch fits
  while (G > 1 && staticB + (size_t)G * GELEMS * 2 > ws_size) G >>= 1;
  int nch = 8 / G;

  cvt_T_kernel<<<dim3(4608 / 32, 768 / 32), 256, 0, stream>>>(w_qkv, w16t, 768, 4608);
  cvt_T_kernel<<<dim3(768 / 32, 768 / 32), 256, 0, stream>>>(w_proj, wpt, 768, 768);

  for (int ch = 0; ch < nch; ch++) {
    int b0 = ch * G;
    gemm_qkv_kernel<<<G * 1152, 256, 0, stream>>>(x + (size_t)b0 * 4096 * 768, w16t, area);
    attn_spat_kernel<<<G * 192, 512, 0, stream>>>(area);
    attn_chan_kernel<<<G * 256, 256, 0, stream>>>(area);
    gemm_proj_kernel<<<G * 192, 256, 0, stream>>>(area, wpt, b_proj,
                                                  out + (size_t)b0 * 4096 * 768);
  }
}

// Round 4
// 757.795 us; speedup vs baseline: 1.0859x; 1.0859x over previous
//
#include <hip/hip_runtime.h>

typedef _Float16 f16;
typedef f16  f16x8 __attribute__((ext_vector_type(8)));
typedef float f32x4 __attribute__((ext_vector_type(4)));

#define S3 3145728LL   // per-batch per-component elems (12*256*16*64 = 4096*768)

__device__ __forceinline__ f32x4 mm(f16x8 a, f16x8 b, f32x4 c) {
  return __builtin_amdgcn_mfma_f32_16x16x32_f16(a, b, c, 0, 0, 0);
}
__device__ __forceinline__ void BAR() { asm volatile("s_barrier" ::: "memory"); }

// ---------------- transpose + fp32->fp16 convert: out[Cc][R] = in[R][Cc] ----
__global__ void cvt_T_kernel(const float* __restrict__ in, f16* __restrict__ out,
                             int R, int Cc) {
  __shared__ float tile[32][33];
  int tc = blockIdx.x, tr = blockIdx.y;
  int lr = threadIdx.x & 31, lw = threadIdx.x >> 5;
  int c0 = tc * 32, r0 = tr * 32;
#pragma unroll
  for (int i = 0; i < 4; i++)
    tile[lw + 8 * i][lr] = in[(size_t)(r0 + lw + 8 * i) * Cc + c0 + lr];
  __syncthreads();
#pragma unroll
  for (int i = 0; i < 4; i++)
    out[(size_t)(c0 + lw + 8 * i) * R + r0 + lr] = (f16)tile[lr][lw + 8 * i];
}

// ---------------- x fp32 -> f16 --------------------------------------------
__global__ void cvt_x_kernel(const float* __restrict__ in, f16* __restrict__ out) {
  size_t i = ((size_t)blockIdx.x * 256 + threadIdx.x) * 8;
  f32x4 a = *(const f32x4*)(in + i);
  f32x4 b = *(const f32x4*)(in + i + 4);
  f16x8 o;
#pragma unroll
  for (int j = 0; j < 4; j++) { o[j] = (f16)a[j]; o[4 + j] = (f16)b[j]; }
  *(f16x8*)(out + i) = o;
}

// ---------------- QKV GEMM: 256x256 tile, BK=64, 8-phase pipelined ----------
#define STG_A(c, q, kt) __builtin_amdgcn_global_load_lds( \
    (const __attribute__((address_space(1))) void*)(aSrc + (size_t)(q) * 49152 + (size_t)(kt) * 64), \
    (__attribute__((address_space(3))) void*)(lds + (c) * 32768 + (q) * 4096 + wave * 512), 16, 0, 0)
#define STG_B(c, q, kt) __builtin_amdgcn_global_load_lds( \
    (const __attribute__((address_space(1))) void*)(bSrc + (size_t)(q) * 49152 + (size_t)(kt) * 64), \
    (__attribute__((address_space(3))) void*)(lds + 16384 + (c) * 32768 + (q) * 4096 + wave * 512), 16, 0, 0)
#define WAIT_LGKM() do { asm volatile("s_waitcnt lgkmcnt(0)" ::: "memory"); \
                         __builtin_amdgcn_sched_barrier(0); } while (0)

__global__ __launch_bounds__(512, 2) void gemm_qkv8(
    const f16* __restrict__ A, const f16* __restrict__ Bt,
    f16* __restrict__ area, long long cstr_) {
  __shared__ f16 lds[65536];   // [buf0: A 32KB | B 32KB][buf1: A | B]
  size_t cstr = (size_t)cstr_;
  int id  = blockIdx.x;
  int cpx = gridDim.x >> 3;
  int id2 = (id & 7) * cpx + (id >> 3);       // XCD swizzle (grid % 8 == 0)
  int sr = id2 / 144, rr = id2 % 144;
  int bm = sr * 8 + (rr & 7), bn = rr >> 3;   // bm 0..G*16-1, bn 0..17

  int tid = threadIdx.x;
  int wave = tid >> 6, lane = tid & 63;
  int l16 = lane & 15, lq = lane >> 4;
  int wr = wave >> 2, wc = wave & 3;          // 2 x 4 wave grid
  int sx  = (l16 & 7) << 4;                   // read-side XOR swizzle (bytes)
  int cb0 = (lq * 16) ^ sx;
  int cb1 = (64 + lq * 16) ^ sx;

  // pre-swizzled global sources (involution: col granule ^= (row&7))
  int scol = ((tid & 7) ^ ((tid >> 3) & 7)) << 3;   // f16 elems
  const f16* aSrc = A  + (size_t)(bm * 256 + (tid >> 3)) * 768 + scol;
  const f16* bSrc = Bt + (size_t)(bn * 256 + (tid >> 3)) * 768 + scol;

  f32x4 zz = {0.f, 0.f, 0.f, 0.f};
  f32x4 acc[8][4];
#pragma unroll
  for (int m = 0; m < 8; m++)
#pragma unroll
    for (int n = 0; n < 4; n++) acc[m][n] = zz;

  // prologue: tile0 fully + tile1 {A quarters 1,3; B quarters 0,1}
  STG_A(0, 0, 0); STG_A(0, 1, 0); STG_A(0, 2, 0); STG_A(0, 3, 0);
  STG_B(0, 0, 0); STG_B(0, 1, 0); STG_B(0, 2, 0); STG_B(0, 3, 0);
  STG_A(1, 1, 1); STG_A(1, 3, 1);
  STG_B(1, 0, 1); STG_B(1, 1, 1);
  asm volatile("s_waitcnt vmcnt(4)" ::: "memory");
  BAR();

  f16x8 af[4][2], ag[4][2], bf[2][2], bg[2][2];
#pragma unroll 2
  for (int t = 0; t < 12; ++t) {
    int c = t & 1, nb = c ^ 1;
    const char* ab = (const char*)lds + c * 65536;
    const char* bb = ab + 32768;
    int rA = wr * 128 + l16;
    int rB = wc * 64 + l16;

    // ---- P1: (mq0, nq0) ----
#pragma unroll
    for (int mf = 0; mf < 4; mf++) {
      af[mf][0] = *(const f16x8*)(ab + (rA + mf * 16) * 128 + cb0);
      af[mf][1] = *(const f16x8*)(ab + (rA + mf * 16) * 128 + cb1);
    }
#pragma unroll
    for (int nf = 0; nf < 2; nf++) {
      bf[nf][0] = *(const f16x8*)(bb + (rB + nf * 16) * 128 + cb0);
      bf[nf][1] = *(const f16x8*)(bb + (rB + nf * 16) * 128 + cb1);
    }
    if (t < 11) { STG_B(nb, 2, t + 1); STG_B(nb, 3, t + 1); }
    BAR(); WAIT_LGKM();
    __builtin_amdgcn_s_setprio(1);
#pragma unroll
    for (int ks = 0; ks < 2; ks++)
#pragma unroll
      for (int mf = 0; mf < 4; mf++)
#pragma unroll
        for (int nf = 0; nf < 2; nf++)
          acc[mf][nf] = mm(af[mf][ks], bf[nf][ks], acc[mf][nf]);
    __builtin_amdgcn_s_setprio(0);
    BAR();

    // ---- P2: (mq1, nq0) ----
#pragma unroll
    for (int mf = 0; mf < 4; mf++) {
      ag[mf][0] = *(const f16x8*)(ab + (rA + 64 + mf * 16) * 128 + cb0);
      ag[mf][1] = *(const f16x8*)(ab + (rA + 64 + mf * 16) * 128 + cb1);
    }
    if (t < 11) { STG_A(nb, 0, t + 1); STG_A(nb, 2, t + 1); }
    BAR(); WAIT_LGKM();
    __builtin_amdgcn_s_setprio(1);
#pragma unroll
    for (int ks = 0; ks < 2; ks++)
#pragma unroll
      for (int mf = 0; mf < 4; mf++)
#pragma unroll
        for (int nf = 0; nf < 2; nf++)
          acc[4 + mf][nf] = mm(ag[mf][ks], bf[nf][ks], acc[4 + mf][nf]);
    __builtin_amdgcn_s_setprio(0);
    BAR();

    // ---- P3: (mq1, nq1) ----
#pragma unroll
    for (int nf = 0; nf < 2; nf++) {
      bg[nf][0] = *(const f16x8*)(bb + (rB + 32 + nf * 16) * 128 + cb0);
      bg[nf][1] = *(const f16x8*)(bb + (rB + 32 + nf * 16) * 128 + cb1);
    }
    if (t < 10) { STG_A(c, 1, t + 2); STG_A(c, 3, t + 2); }
    BAR(); WAIT_LGKM();
    __builtin_amdgcn_s_setprio(1);
#pragma unroll
    for (int ks = 0; ks < 2; ks++)
#pragma unroll
      for (int mf = 0; mf < 4; mf++)
#pragma unroll
        for (int nf = 0; nf < 2; nf++)
          acc[4 + mf][2 + nf] = mm(ag[mf][ks], bg[nf][ks], acc[4 + mf][2 + nf]);
    __builtin_amdgcn_s_setprio(0);
    BAR();

    // ---- P4: (mq0, nq1) ----
#pragma unroll
    for (int mf = 0; mf < 4; mf++) {
      af[mf][0] = *(const f16x8*)(ab + (rA + mf * 16) * 128 + cb0);
      af[mf][1] = *(const f16x8*)(ab + (rA + mf * 16) * 128 + cb1);
    }
    if (t < 10) { STG_B(c, 0, t + 2); STG_B(c, 1, t + 2); }
    BAR(); WAIT_LGKM();
    __builtin_amdgcn_s_setprio(1);
#pragma unroll
    for (int ks = 0; ks < 2; ks++)
#pragma unroll
      for (int mf = 0; mf < 4; mf++)
#pragma unroll
        for (int nf = 0; nf < 2; nf++)
          acc[mf][2 + nf] = mm(af[mf][ks], bg[nf][ks], acc[mf][2 + nf]);
    __builtin_amdgcn_s_setprio(0);
    // Tail fix: for t>=10, P3/P4 issue no t+2 staging, so vmcnt(4) would leave
    // tile t+1's OWN P1/P2 loads outstanding -> t=11 could read unlanded LDS.
    if (t < 10) asm volatile("s_waitcnt vmcnt(4)" ::: "memory");
    else        asm volatile("s_waitcnt vmcnt(0)" ::: "memory");
    BAR();
  }

  // permuting epilogue: col = s*768 + h*64 + d  (s: qc,kc,qs,ks,vc,vs)
  int g = (bm * 256) >> 12;
  size_t goff = (size_t)g * S3;
#pragma unroll
  for (int ni = 0; ni < 4; ni++) {
    int col = bn * 256 + wc * 64 + ni * 16 + l16;
    int s = col / 768;
    int rem = col - s * 768;
    int h = rem >> 6, d = rem & 63;
#pragma unroll
    for (int mi = 0; mi < 8; mi++) {
#pragma unroll
      for (int r = 0; r < 4; r++) {
        int row = wr * 128 + (mi >> 2) * 64 + (mi & 3) * 16 + lq * 4 + r;
        int token = ((bm * 256) & 4095) + row;
        int n = token >> 4, cc = token & 15;
        size_t off;
        if (s == 0)      off = 0 * cstr + goff + (size_t)(((h * 256 + n) * 16 + cc) * 64 + d);
        else if (s == 1) off = 1 * cstr + goff + (size_t)(((h * 256 + n) * 16 + cc) * 64 + d);
        else if (s == 2) off = 3 * cstr + goff + (size_t)(((h * 16 + cc) * 256 + n) * 64 + d);
        else if (s == 3) off = 4 * cstr + goff + (size_t)(((h * 16 + cc) * 256 + n) * 64 + d);
        else if (s == 4) off = 2 * cstr + goff + (size_t)(((h * 256 + n) * 64 + d) * 16 + cc);
        else             off = 5 * cstr + goff + (size_t)(((h * 16 + cc) * 64 + d) * 256 + n);
        area[off] = (f16)acc[mi][ni][r];
      }
    }
  }
}

// ---------------- spatial attention: per (g,h,c), flash over N=256 ----------
__global__ __launch_bounds__(512) void attn_spat_kernel(f16* __restrict__ area,
                                                        long long cstr_) {
  size_t cstr = (size_t)cstr_;
  int blk = blockIdx.x;
  int g = blk / 192, rem = blk % 192;
  int h = rem >> 4, c = rem & 15;
  size_t goff = (size_t)g * S3;
  const f16* qs = area + 3 * cstr + goff + (size_t)((h * 16 + c) * 256) * 64;
  const f16* ks = area + 4 * cstr + goff + (size_t)((h * 16 + c) * 256) * 64;
  const f16* vs = area + 5 * cstr + goff + (size_t)((h * 16 + c) * 64) * 256; // [d][n]
  f16* xs = area + 6 * cstr + goff + (size_t)((h * 16 + c) * 256) * 64;

  int wave = threadIdx.x >> 6, lane = threadIdx.x & 63;
  int l16 = lane & 15, lq = lane >> 4;
  __shared__ f16 plds[8][32][40];

  f32x4 zz = {0.f, 0.f, 0.f, 0.f};
  f16x8 aq[2][2];
#pragma unroll
  for (int m = 0; m < 2; m++)
#pragma unroll
    for (int kd = 0; kd < 2; kd++)
      aq[m][kd] = *(const f16x8*)&qs[(size_t)(wave * 32 + m * 16 + l16) * 64 + kd * 32 + lq * 8];

  f32x4 o[2][4];
  float mrow[2][4], lrow[2][4];
#pragma unroll
  for (int m = 0; m < 2; m++) {
#pragma unroll
    for (int n = 0; n < 4; n++) o[m][n] = zz;
#pragma unroll
    for (int r = 0; r < 4; r++) { mrow[m][r] = -1e30f; lrow[m][r] = 0.f; }
  }

  for (int kc = 0; kc < 8; kc++) {
    int k0 = kc * 32;
    f16x8 bk00 = *(const f16x8*)&ks[(size_t)(k0 + l16) * 64 + lq * 8];
    f16x8 bk01 = *(const f16x8*)&ks[(size_t)(k0 + l16) * 64 + 32 + lq * 8];
    f16x8 bk10 = *(const f16x8*)&ks[(size_t)(k0 + 16 + l16) * 64 + lq * 8];
    f16x8 bk11 = *(const f16x8*)&ks[(size_t)(k0 + 16 + l16) * 64 + 32 + lq * 8];
    f32x4 st[2][2];
#pragma unroll
    for (int m = 0; m < 2; m++) {
      st[m][0] = mm(aq[m][1], bk01, mm(aq[m][0], bk00, zz));
      st[m][1] = mm(aq[m][1], bk11, mm(aq[m][0], bk10, zz));
    }
#pragma unroll
    for (int m = 0; m < 2; m++) {
#pragma unroll
      for (int r = 0; r < 4; r++) {
        float s0 = st[m][0][r] * 0.125f, s1 = st[m][1][r] * 0.125f;
        float t = fmaxf(s0, s1);
        t = fmaxf(t, __shfl_xor(t, 1));
        t = fmaxf(t, __shfl_xor(t, 2));
        t = fmaxf(t, __shfl_xor(t, 4));
        t = fmaxf(t, __shfl_xor(t, 8));
        float mold = mrow[m][r];
        float mnew = fmaxf(mold, t);
        float fac  = __expf(mold - mnew);
        mrow[m][r] = mnew;
        float p0 = __expf(s0 - mnew), p1 = __expf(s1 - mnew);
        lrow[m][r] = lrow[m][r] * fac + p0 + p1;
        o[m][0][r] *= fac; o[m][1][r] *= fac; o[m][2][r] *= fac; o[m][3][r] *= fac;
        int prow = m * 16 + lq * 4 + r;
        plds[wave][prow][l16]      = (f16)p0;
        plds[wave][prow][16 + l16] = (f16)p1;
      }
    }
    f16x8 ap0 = *(const f16x8*)&plds[wave][l16][lq * 8];
    f16x8 ap1 = *(const f16x8*)&plds[wave][16 + l16][lq * 8];
#pragma unroll
    for (int n = 0; n < 4; n++) {
      f16x8 bv = *(const f16x8*)&vs[(size_t)(n * 16 + l16) * 256 + k0 + lq * 8];
      o[0][n] = mm(ap0, bv, o[0][n]);
      o[1][n] = mm(ap1, bv, o[1][n]);
    }
  }
#pragma unroll
  for (int m = 0; m < 2; m++)
#pragma unroll
    for (int r = 0; r < 4; r++) {
      float l = lrow[m][r];
      l += __shfl_xor(l, 1);
      l += __shfl_xor(l, 2);
      l += __shfl_xor(l, 4);
      l += __shfl_xor(l, 8);
      lrow[m][r] = 1.0f / l;
    }
#pragma unroll
  for (int m = 0; m < 2; m++)
#pragma unroll
    for (int n = 0; n < 4; n++)
#pragma unroll
      for (int r = 0; r < 4; r++) {
        int row = wave * 32 + m * 16 + lq * 4 + r;
        xs[(size_t)row * 64 + n * 16 + l16] = (f16)(o[m][n][r] * lrow[m][r]);
      }
}

// ---------------- channel attention + combine: per (g,n), 12 heads ----------
__global__ __launch_bounds__(256) void attn_chan_kernel(f16* __restrict__ area,
                                                        long long cstr_) {
  size_t cstr = (size_t)cstr_;
  int blk = blockIdx.x;
  int g = blk >> 8, n = blk & 255;
  size_t goff = (size_t)g * S3;
  int wave = threadIdx.x >> 6, lane = threadIdx.x & 63;
  int l16 = lane & 15, lq = lane >> 4;
  __shared__ f16 plds[4][16][40];
  if (lane < 16) {
#pragma unroll
    for (int j = 0; j < 16; j++) plds[wave][lane][16 + j] = (f16)0.f;  // zero K-pad
  }
  const f16* xs = area + 6 * cstr + goff;
  f16* prod = area + 7 * cstr + goff;
  f32x4 zz = {0.f, 0.f, 0.f, 0.f};
  for (int hi = 0; hi < 3; hi++) {
    int h = wave + hi * 4;
    const f16* q = area + 0 * cstr + goff + (size_t)((h * 256 + n) * 16) * 64;
    const f16* k = area + 1 * cstr + goff + (size_t)((h * 256 + n) * 16) * 64;
    const f16* v = area + 2 * cstr + goff + (size_t)((h * 256 + n) * 64) * 16; // [d][c]
    f16x8 a0 = *(const f16x8*)&q[l16 * 64 + lq * 8];
    f16x8 a1 = *(const f16x8*)&q[l16 * 64 + 32 + lq * 8];
    f16x8 b0 = *(const f16x8*)&k[l16 * 64 + lq * 8];
    f16x8 b1 = *(const f16x8*)&k[l16 * 64 + 32 + lq * 8];
    f32x4 s = mm(a1, b1, mm(a0, b0, zz));
    float p[4];
#pragma unroll
    for (int r = 0; r < 4; r++) {
      float t = s[r] * 0.125f;
      float mx = t;
      mx = fmaxf(mx, __shfl_xor(mx, 1));
      mx = fmaxf(mx, __shfl_xor(mx, 2));
      mx = fmaxf(mx, __shfl_xor(mx, 4));
      mx = fmaxf(mx, __shfl_xor(mx, 8));
      float e = __expf(t - mx);
      float sum = e;
      sum += __shfl_xor(sum, 1);
      sum += __shfl_xor(sum, 2);
      sum += __shfl_xor(sum, 4);
      sum += __shfl_xor(sum, 8);
      p[r] = e / sum;
    }
#pragma unroll
    for (int r = 0; r < 4; r++)
      plds[wave][lq * 4 + r][l16] = (f16)p[r];
    f16x8 ap = *(const f16x8*)&plds[wave][l16][lq * 8]; // k>=16 are zeros
#pragma unroll
    for (int nt = 0; nt < 4; nt++) {
      f16x8 bv = *(const f16x8*)&v[(nt * 16 + l16) * 16 + lq * 8];
      f32x4 o = mm(ap, bv, zz);
#pragma unroll
      for (int r = 0; r < 4; r++) {
        int cq = lq * 4 + r, d = nt * 16 + l16;
        float xsv = (float)xs[(size_t)((h * 16 + cq) * 256 + n) * 64 + d];
        prod[(size_t)n * 12288 + h * 1024 + cq * 64 + d] = (f16)(o[r] * xsv);
      }
    }
  }
}

// ---------------- proj GEMM: out[G*4096,768] = prod * wpt^T + bias ----------
__global__ __launch_bounds__(256) void gemm_proj_kernel(
    const f16* __restrict__ area, const f16* __restrict__ Bt,
    const float* __restrict__ bias, float* __restrict__ Cout, long long cstr_) {
  size_t cstr = (size_t)cstr_;
  __shared__ f16 Asm[128 * 32];
  __shared__ f16 Bsm[128 * 32];
  const int nbn = 6;
  int nwg = gridDim.x;
  int id  = blockIdx.x;
  int cpx = nwg >> 3;
  int id2 = (id & 7) * cpx + (id >> 3);
  int sr  = id2 / (8 * nbn);
  int rr_ = id2 % (8 * nbn);
  int bm  = sr * 8 + (rr_ & 7);
  int bn  = rr_ >> 3;

  int tid = threadIdx.x;
  int wave = tid >> 6, lane = tid & 63;
  int l16 = lane & 15, lq = lane >> 4;
  int wr = wave >> 1, wc = wave & 1;

  int srow = tid >> 1;
  int skh  = (tid & 1) << 4;
  const f16* Ap = area + 7 * cstr + (size_t)(bm * 128 + srow) * 768 + skh;
  const f16* Bp = Bt + (size_t)(bn * 128 + srow) * 768 + skh;
  f16* AsmW = &Asm[srow * 32 + skh];
  f16* BsmW = &Bsm[srow * 32 + skh];

  f32x4 zz = {0.f, 0.f, 0.f, 0.f};
  f32x4 acc[4][4];
#pragma unroll
  for (int m = 0; m < 4; m++)
#pragma unroll
    for (int n = 0; n < 4; n++) acc[m][n] = zz;

  for (int kt = 0; kt < 24; kt++) {
    f16x8 a0 = *(const f16x8*)(Ap + kt * 32);
    f16x8 a1 = *(const f16x8*)(Ap + kt * 32 + 8);
    f16x8 b0 = *(const f16x8*)(Bp + kt * 32);
    f16x8 b1 = *(const f16x8*)(Bp + kt * 32 + 8);
    __syncthreads();
    *(f16x8*)AsmW       = a0;
    *(f16x8*)(AsmW + 8) = a1;
    *(f16x8*)BsmW       = b0;
    *(f16x8*)(BsmW + 8) = b1;
    __syncthreads();
    f16x8 af[4], bf[4];
#pragma unroll
    for (int m = 0; m < 4; m++)
      af[m] = *(const f16x8*)&Asm[(wr * 64 + m * 16 + l16) * 32 + lq * 8];
#pragma unroll
    for (int n = 0; n < 4; n++)
      bf[n] = *(const f16x8*)&Bsm[(wc * 64 + n * 16 + l16) * 32 + lq * 8];
#pragma unroll
    for (int m = 0; m < 4; m++)
#pragma unroll
      for (int n = 0; n < 4; n++)
        acc[m][n] = mm(af[m], bf[n], acc[m][n]);
  }

#pragma unroll
  for (int nt = 0; nt < 4; nt++) {
    int col = bn * 128 + wc * 64 + nt * 16 + l16;
    float bb = bias[col];
#pragma unroll
    for (int m = 0; m < 4; m++) {
#pragma unroll
      for (int r = 0; r < 4; r++) {
        int row = bm * 128 + wr * 64 + m * 16 + lq * 4 + r;
        Cout[(size_t)row * 768 + col] = acc[m][nt][r] + bb;
      }
    }
  }
}

// ---------------- host ------------------------------------------------------
extern "C" void kernel_launch(void* const* d_in, const int* in_sizes, int n_in,
                              void* d_out, int out_size, void* d_ws, size_t ws_size,
                              hipStream_t stream) {
  const float* x      = (const float*)d_in[0];
  const float* w_qkv  = (const float*)d_in[1];
  const float* w_proj = (const float*)d_in[2];
  const float* b_proj = (const float*)d_in[3];
  float* out = (float*)d_out;
  f16* ws = (f16*)d_ws;

  const size_t W16T = 4608ull * 768;
  const size_t WPT  = 768ull * 768;
  f16* w16t = ws;
  f16* wpt  = ws + W16T;
  f16* area = wpt + WPT;

  int G = 8;  // batches per chunk; shrink until scratch fits
  while (G > 1 && (W16T + WPT + 8ull * G * S3) * 2 > ws_size) G >>= 1;
  int nch = 8 / G;
  long long cstr = (long long)G * S3;
  f16* x16 = area + 7 * (size_t)cstr;   // aliases comp7 (prod) - dead until attn_chan

  cvt_T_kernel<<<dim3(144, 24), 256, 0, stream>>>(w_qkv, w16t, 768, 4608);
  cvt_T_kernel<<<dim3(24, 24), 256, 0, stream>>>(w_proj, wpt, 768, 768);

  for (int ch = 0; ch < nch; ch++) {
    size_t b0 = (size_t)ch * G;
    cvt_x_kernel<<<G * 1536, 256, 0, stream>>>(x + b0 * S3, x16);
    gemm_qkv8<<<G * 288, 512, 0, stream>>>(x16, w16t, area, cstr);
    attn_spat_kernel<<<G * 192, 512, 0, stream>>>(area, cstr);
    attn_chan_kernel<<<G * 256, 256, 0, stream>>>(area, cstr);
    gemm_proj_kernel<<<G * 192, 256, 0, stream>>>(area, wpt, b_proj,
                                                  out + b0 * S3, cstr);
  }
}